// Round 7
// baseline (96.194 us; speedup 1.0000x reference)
//
#include <hip/hip_runtime.h>

// DelayedXOR SH-SNN forward. Chains (b,h) fully independent
// (s_g.reshape(B,H) maps (g,j)->h=g*16+j one-to-one). One thread per chain.
//
// R6 -> R7: R6 ran at ~83 cyc/step vs ~36 issue floor == near-program-order
// execution of a serial 13-op chain (~6 cyc per dependent op). The backend
// won't software-pipeline it; do it at source level. Soma step s consumes
// only sf_s, so SKEW THE SOMA CHAIN BY ONE STEP: iteration i interleaves
//   v-chain step i      (reads sf_{i-1}, makes sf_i)      [6 ops serial]
//   soma-chain step i-1 (reads sf_{i-1}, V, Sf)           [7 ops serial]
// -- two INDEPENDENT chains, alternated per instruction -> dependent ops
// are >=2 instrs apart -> 4-cyc ALU latency covered by issue. Keeps 512
// waves (unlike R5's 2-chains trade). Boundary handling: iteration 0's
// soma step "-1" on zero state is an exact no-op (V=+0, Sf=0); epilogue
// runs soma step 1023; acc window shifts one iteration (tile 48 skips its
// first soma step = step 767).
//
// Correctness: bit-exact fp32 vs numpy reference (absmax 0.0 in R1-R6).
// - fp contract OFF everywhere; exact reference expression order
// - spike = med3(ceil(v-1),0,1): exact (Sterbenz on [1,2]); -0 harmless
// - (1-alpha)*integ as sf*oms: exact since sf in {0,1}
// - sigmoid in double, rounded once to fp32

__device__ __forceinline__ float fmed3(float a, float b, float c)
{
    return __builtin_amdgcn_fmed3f(a, b, c);
}

__device__ __forceinline__ void make_e(const float4* s, int k, float (&e)[16],
                                       float w0, float w1, float omg)
{
#pragma clang fp contract(off)
#pragma unroll
    for (int i = 0; i < 8; ++i) {
        float4 q = s[k * 8 + i];
        e[2*i + 0] = omg * ((q.x * w0) + (q.y * w1));
        e[2*i + 1] = omg * ((q.z * w0) + (q.w * w1));
    }
}

// ACCMODE: 0 = no acc, 1 = acc every soma step, 2 = acc all but first (j==0)
template <int ACCMODE>
__device__ __forceinline__ void tile16_pipe(const float (&e)[16],
                                            float ag, float as, float oms,
                                            float& v, float& sf,
                                            float& V, float& Sf, float& acc)
{
#pragma clang fp contract(off)
#pragma unroll
    for (int j = 0; j < 16; ++j) {
        // A: v-chain step i          B: soma-chain step i-1 (uses old sf,V,Sf)
        float t1 = ag * v;            float a1 = as * V;
        float u  = t1 + e[j];         float a2 = sf * oms;
        float vn = u  - sf;           float a3 = a1 + a2;
        float d1 = vn - 1.0f;         float Vn = a3 - Sf;
        float c1 = __builtin_ceilf(d1);   float d2 = Vn - 1.0f;
        float sfn = fmed3(c1, 0.0f, 1.0f);float c2 = __builtin_ceilf(d2);
                                      float Sfn = fmed3(c2, 0.0f, 1.0f);
        if (ACCMODE == 1 || (ACCMODE == 2 && j > 0))
            acc += Sfn;
        v = vn; sf = sfn; V = Vn; Sf = Sfn;
    }
}

__global__ __launch_bounds__(64, 1) void snn_fwd(
    const float* __restrict__ x,       // [B, T, 2]
    const float* __restrict__ Wg,      // [2, 16, 2] == [h][2]
    const float* __restrict__ tau_m,   // [2, 16] == [h]
    const float* __restrict__ soma,    // [32]
    const float* __restrict__ W_out,   // [1, 32]
    const float* __restrict__ b_out,   // [1]
    float* __restrict__ out)           // [B, 1]
{
#pragma clang fp contract(off)
    // Two x rows per block (16 KB). Lanes 0-31: b=2*blk, lanes 32-63: b=2*blk+1.
    __shared__ float4 sx[1024];

    const int tid  = threadIdx.x;
    const int h    = tid & 31;
    const int half = tid >> 5;
    const int b    = (blockIdx.x << 1) | half;

    const float4* gx = (const float4*)(x + (size_t)blockIdx.x * 4096);
#pragma unroll
    for (int k = 0; k < 16; ++k)
        sx[k * 64 + tid] = gx[k * 64 + tid];

    const float w0 = Wg[2*h + 0];
    const float w1 = Wg[2*h + 1];
    const float ag  = (float)(1.0 / (1.0 + exp(-(double)tau_m[h])));
    const float omg = 1.0f - ag;
    const float as  = (float)(1.0 / (1.0 + exp(-(double)soma[h])));
    const float oms = 1.0f - as;

    __syncthreads();

    const float4* sbase = sx + half * 512;

    float v = 0.f, sf = 0.f, V = 0.f, Sf = 0.f, acc = 0.f;

    float eA[16], eB[16];
    make_e(sbase, 0, eA, w0, w1, omg);

    // Tiles of 16 iterations. Iteration i = v-step i + soma-step i-1.
    // tiles 0..47: soma steps <= 766 -> no acc
    for (int k = 0; k < 48; k += 2) {
        make_e(sbase, k + 1, eB, w0, w1, omg);
        tile16_pipe<0>(eA, ag, as, oms, v, sf, V, Sf, acc);
        make_e(sbase, k + 2, eA, w0, w1, omg);
        tile16_pipe<0>(eB, ag, as, oms, v, sf, V, Sf, acc);
    }
    // tile 48: soma steps 767..782 -> acc all but first
    make_e(sbase, 49, eB, w0, w1, omg);
    tile16_pipe<2>(eA, ag, as, oms, v, sf, V, Sf, acc);
    // tiles 49..63: soma steps 783..1022 -> acc all
    make_e(sbase, 50, eA, w0, w1, omg);
    tile16_pipe<1>(eB, ag, as, oms, v, sf, V, Sf, acc);
    for (int k = 50; k < 62; k += 2) {
        make_e(sbase, k + 1, eB, w0, w1, omg);
        tile16_pipe<1>(eA, ag, as, oms, v, sf, V, Sf, acc);
        make_e(sbase, k + 2, eA, w0, w1, omg);
        tile16_pipe<1>(eB, ag, as, oms, v, sf, V, Sf, acc);
    }
    make_e(sbase, 63, eB, w0, w1, omg);
    tile16_pipe<1>(eA, ag, as, oms, v, sf, V, Sf, acc);
    tile16_pipe<1>(eB, ag, as, oms, v, sf, V, Sf, acc);

    // epilogue: soma step 1023 (consumes final sf), accumulates
    {
        float a1 = as * V;
        float a2 = sf * oms;
        float a3 = a1 + a2;
        float Vn = a3 - Sf;
        float Sfn = fmed3(__builtin_ceilf(Vn - 1.0f), 0.0f, 1.0f);
        acc += Sfn;
    }

    // out[b] = sum_h acc[h] * W_out[h] + b_out; xor-reduce within 32-lane half.
    float val = acc * W_out[h];
#pragma unroll
    for (int m = 16; m >= 1; m >>= 1)
        val += __shfl_xor(val, m, 64);
    if ((tid & 31) == 0)
        out[b] = val + b_out[0];
}

extern "C" void kernel_launch(void* const* d_in, const int* in_sizes, int n_in,
                              void* d_out, int out_size, void* d_ws, size_t ws_size,
                              hipStream_t stream)
{
    const float* x     = (const float*)d_in[0];
    const float* Wg    = (const float*)d_in[1];
    const float* tau_m = (const float*)d_in[2];
    const float* soma  = (const float*)d_in[3];
    const float* W_out = (const float*)d_in[4];
    const float* b_out = (const float*)d_in[5];
    float* out = (float*)d_out;

    // 512 blocks x 64 threads = one (b,h) chain per thread (2 waves/CU).
    dim3 grid(512), block(64);
    hipLaunchKernelGGL(snn_fwd, grid, block, 0, stream,
                       x, Wg, tau_m, soma, W_out, b_out, out);
}

// Round 8
// 89.752 us; speedup vs baseline: 1.0718x; 1.0718x over previous
//
#include <hip/hip_runtime.h>

// DelayedXOR SH-SNN forward. Chains (b,h) fully independent; 1 thread/chain.
//
// R7 -> R8: measured invariant: ~4.3-4.4 cyc per VALU instruction per wave
// REGARDLESS of ILP (R5/R6/R7) -> solo-wave issue cadence is fixed; wall time
// is proportional to instructions/step. So cut instructions with PACKED FP32
// (v_pk_*_f32: 2 floats/instr, same cadence). Using R7's validated skew, the
// pair [v-step i, soma-step i-1] is independent -> pack state W=[v,V],
// spikes SF=[sf,Sf], coeffs [ag,as]; core becomes 3 pk ops + packed spike.
// make_e packed across adjacent timesteps via x0/x1 plane-split LDS layout.
// ~13 instr/step vs R7's ~19.
//
// Correctness: packed ops are lane-wise IEEE fp32 -> bit-exact per-op vs
// reference (absmax 0.0 in R1-R7). Skew boundary logic identical to R7
// (soma step -1 on zero state is an exact no-op; epilogue runs soma step
// 1023; tile 48 skips its first soma step = step 767).
// - fp contract OFF (no pk_fma fusion)
// - spike = med3(ceil(v-1),0,1): exact; -0 harmless
// - (1-alpha)*integ as sf*oms: exact since sf in {0,1}
// - sigmoid in double, rounded once to fp32

typedef float v2f __attribute__((ext_vector_type(2)));

__device__ __forceinline__ float fmed3(float a, float b, float c)
{
    return __builtin_amdgcn_fmed3f(a, b, c);
}

// e[16] for tile k from plane-split LDS, packed 2 timesteps/instr.
__device__ __forceinline__ void make_e(const float4* px0, const float4* px1,
                                       int k, float (&e)[16],
                                       v2f w02, v2f w12, v2f om2)
{
#pragma clang fp contract(off)
#pragma unroll
    for (int i4 = 0; i4 < 4; ++i4) {
        float4 a = px0[k * 4 + i4];   // x0 for steps 4*i4 .. 4*i4+3
        float4 c = px1[k * 4 + i4];   // x1 for same steps
        v2f pa0 = {a.x, a.y}, pa1 = {a.z, a.w};
        v2f pc0 = {c.x, c.y}, pc1 = {c.z, c.w};
        v2f E0 = om2 * ((pa0 * w02) + (pc0 * w12));   // pk_mul,pk_mul,pk_add,pk_mul
        v2f E1 = om2 * ((pa1 * w02) + (pc1 * w12));
        e[4*i4 + 0] = E0.x; e[4*i4 + 1] = E0.y;
        e[4*i4 + 2] = E1.x; e[4*i4 + 3] = E1.y;
    }
}

// ACCMODE: 0 = no acc, 1 = acc every soma step, 2 = acc all but first (j==0)
// Iteration j: W=[v_{j-1}, V_{j-2}], SF=[sf_{j-1}, Sf_{j-2}] on entry.
template <int ACCMODE>
__device__ __forceinline__ void tile16(const float (&e)[16],
                                       v2f AL, float oms,
                                       v2f& W, v2f& SF, float& acc)
{
#pragma clang fp contract(off)
    const v2f one2 = {1.0f, 1.0f};
#pragma unroll
    for (int j = 0; j < 16; ++j) {
        float q = SF.x * oms;            // sf_{j-1} * (1-as), exact (sf in {0,1})
        v2f P = AL * W;                  // [ag*v, as*V]        pk_mul
        v2f A = {e[j], q};
        P = P + A;                       // [+e, +q]            pk_add
        W = P - SF;                      // [-sf, -Sf]          pk_sub
        v2f D = W - one2;                //                     pk_add(-1)
        v2f C = {__builtin_ceilf(D.x), __builtin_ceilf(D.y)};
        SF = (v2f){fmed3(C.x, 0.0f, 1.0f), fmed3(C.y, 0.0f, 1.0f)};
        if (ACCMODE == 1 || (ACCMODE == 2 && j > 0))
            acc += SF.y;                 // soma spike Sf_{j-1}
    }
}

__global__ __launch_bounds__(64, 1) void snn_fwd(
    const float* __restrict__ x,       // [B, T, 2]
    const float* __restrict__ Wg,      // [2, 16, 2] == [h][2]
    const float* __restrict__ tau_m,   // [2, 16] == [h]
    const float* __restrict__ soma,    // [32]
    const float* __restrict__ W_out,   // [1, 32]
    const float* __restrict__ b_out,   // [1]
    float* __restrict__ out)           // [B, 1]
{
#pragma clang fp contract(off)
    // Plane-split LDS: x0 and x1 separated so adjacent timesteps are
    // register-adjacent after a float4 read (packed make_e needs [x0_t,x0_t+1]).
    __shared__ float sx0[2][1024];
    __shared__ float sx1[2][1024];

    const int tid  = threadIdx.x;
    const int h    = tid & 31;
    const int half = tid >> 5;
    const int b    = (blockIdx.x << 1) | half;

    // Cooperative staging with transpose: float4 i covers row i>>9, timestep
    // pair p=i&511 (steps 2p,2p+1) as (x0,x1,x0',x1').
    const float4* gx = (const float4*)(x + (size_t)blockIdx.x * 4096);
#pragma unroll
    for (int k = 0; k < 16; ++k) {
        int i = k * 64 + tid;
        int row = i >> 9, p = i & 511;
        float4 q = gx[i];
        *(float2*)&sx0[row][2*p] = make_float2(q.x, q.z);
        *(float2*)&sx1[row][2*p] = make_float2(q.y, q.w);
    }

    const float w0 = Wg[2*h + 0];
    const float w1 = Wg[2*h + 1];
    const float ag  = (float)(1.0 / (1.0 + exp(-(double)tau_m[h])));
    const float omg = 1.0f - ag;
    const float as  = (float)(1.0 / (1.0 + exp(-(double)soma[h])));
    const float oms = 1.0f - as;

    const v2f w02 = {w0, w0}, w12 = {w1, w1}, om2 = {omg, omg};
    const v2f AL  = {ag, as};

    __syncthreads();

    const float4* px0 = (const float4*)sx0[half];
    const float4* px1 = (const float4*)sx1[half];

    v2f W  = {0.f, 0.f};   // [v_i, V_{i-1}]
    v2f SF = {0.f, 0.f};   // [sf_i, Sf_{i-1}]
    float acc = 0.f;

    float eA[16], eB[16];
    make_e(px0, px1, 0, eA, w02, w12, om2);

    // tiles 0..47: soma steps <= 766 -> no acc
    for (int k = 0; k < 48; k += 2) {
        make_e(px0, px1, k + 1, eB, w02, w12, om2);
        tile16<0>(eA, AL, oms, W, SF, acc);
        make_e(px0, px1, k + 2, eA, w02, w12, om2);
        tile16<0>(eB, AL, oms, W, SF, acc);
    }
    // tile 48: soma steps 767..782 -> acc all but first
    make_e(px0, px1, 49, eB, w02, w12, om2);
    tile16<2>(eA, AL, oms, W, SF, acc);
    // tiles 49..63: acc all
    make_e(px0, px1, 50, eA, w02, w12, om2);
    tile16<1>(eB, AL, oms, W, SF, acc);
    for (int k = 50; k < 62; k += 2) {
        make_e(px0, px1, k + 1, eB, w02, w12, om2);
        tile16<1>(eA, AL, oms, W, SF, acc);
        make_e(px0, px1, k + 2, eA, w02, w12, om2);
        tile16<1>(eB, AL, oms, W, SF, acc);
    }
    make_e(px0, px1, 63, eB, w02, w12, om2);
    tile16<1>(eA, AL, oms, W, SF, acc);
    tile16<1>(eB, AL, oms, W, SF, acc);

    // epilogue: soma step 1023 (consumes final sf = SF.x)
    {
        float a1 = as * W.y;
        float a2 = SF.x * oms;
        float a3 = a1 + a2;
        float Vn = a3 - SF.y;
        float Sfn = fmed3(__builtin_ceilf(Vn - 1.0f), 0.0f, 1.0f);
        acc += Sfn;
    }

    // out[b] = sum_h acc[h] * W_out[h] + b_out; xor-reduce within 32-lane half.
    float val = acc * W_out[h];
#pragma unroll
    for (int m = 16; m >= 1; m >>= 1)
        val += __shfl_xor(val, m, 64);
    if ((tid & 31) == 0)
        out[b] = val + b_out[0];
}

extern "C" void kernel_launch(void* const* d_in, const int* in_sizes, int n_in,
                              void* d_out, int out_size, void* d_ws, size_t ws_size,
                              hipStream_t stream)
{
    const float* x     = (const float*)d_in[0];
    const float* Wg    = (const float*)d_in[1];
    const float* tau_m = (const float*)d_in[2];
    const float* soma  = (const float*)d_in[3];
    const float* W_out = (const float*)d_in[4];
    const float* b_out = (const float*)d_in[5];
    float* out = (float*)d_out;

    // 512 blocks x 64 threads = one (b,h) chain per thread.
    dim3 grid(512), block(64);
    hipLaunchKernelGGL(snn_fwd, grid, block, 0, stream,
                       x, Wg, tau_m, soma, W_out, b_out, out);
}